// Round 3
// baseline (483.966 us; speedup 1.0000x reference)
//
#include <hip/hip_runtime.h>
#include <cstdint>
#include <cstddef>

typedef unsigned short u16;
typedef __attribute__((ext_vector_type(8))) short bf16x8;
typedef __attribute__((ext_vector_type(4))) float f32x4;

#define DEV static __device__ __forceinline__

DEV void gload_lds16(const void* g, void* l) {
  __builtin_amdgcn_global_load_lds((const __attribute__((address_space(1))) void*)g,
                                   (__attribute__((address_space(3))) void*)l, 16, 0, 0);
}

DEV u16 f2bf(float f) {  // RNE fp32 -> bf16 (finite inputs)
  unsigned x = __float_as_uint(f);
  return (u16)((x + 0x7FFFu + ((x >> 16) & 1u)) >> 16);
}

DEV unsigned cvtpk(float lo, float hi) {  // bf16(lo) in [15:0], bf16(hi) in [31:16]
  unsigned r;
  asm("v_cvt_pk_bf16_f32 %0, %1, %2" : "=v"(r) : "v"(lo), "v"(hi));
  return r;
}

#if __has_builtin(__builtin_amdgcn_exp2f)
DEV float fexp2(float x) { return __builtin_amdgcn_exp2f(x); }
#else
DEV float fexp2(float x) { return exp2f(x); }
#endif

// ---------------- fp32 -> bf16 convert, 3 buffers in one launch ----------------
__global__ __launch_bounds__(256) void cvt3(const float* __restrict__ a, u16* __restrict__ da,
                                            const float* __restrict__ b, u16* __restrict__ db,
                                            const float* __restrict__ c, u16* __restrict__ dc) {
  int bid = blockIdx.x;
  const float* s;
  u16* d;
  int base;
  if (bid < 4096) { s = a; d = da; base = bid; }
  else if (bid < 7168) { s = b; d = db; base = bid - 4096; }
  else { s = c; d = dc; base = bid - 7168; }
  const int i = (base * 256 + (int)threadIdx.x) * 4;
  float4 v = *(const float4*)(s + i);
  uint2 p;
  p.x = (unsigned)f2bf(v.x) | ((unsigned)f2bf(v.y) << 16);
  p.y = (unsigned)f2bf(v.z) | ((unsigned)f2bf(v.w) << 16);
  *(uint2*)(d + i) = p;
}

// ---------------- GEMM: C = A * B^T (+bias) ----------------
// A[M][K] bf16 row-major, Bm[N][K] bf16 row-major.
// EPI 0: Cout = float[M][N], v + bias[e]
// EPI 1: QKV scatter: Q,K -> [which][b*16+h][s][d] bf16; V -> Vt[b*16+h][d][s] (transposed,
//        packed uint2 stores over 4 consecutive s).
template <int EPI, int BM, int BN>
__global__ __launch_bounds__(256) void gemm_bt(const u16* __restrict__ A,
                                               const u16* __restrict__ Bm,
                                               const float* __restrict__ bias,
                                               void* __restrict__ Cout,
                                               u16* __restrict__ Vt,
                                               int M, int N, int K) {
  __shared__ u16 As[2][BM * 32];
  __shared__ u16 Bs[2][BN * 32];
  constexpr int MT = BM / 32, NT = BN / 32;
  const int cpx = (int)gridDim.x >> 3;
  const int bid = ((int)blockIdx.x & 7) * cpx + ((int)blockIdx.x >> 3);  // XCD chunking
  const int nb = N / BN;
  const int m0 = (bid / nb) * BM;
  const int n0 = (bid % nb) * BN;
  const int tid = threadIdx.x;
  const int w = tid >> 6, lane = tid & 63;
  const int wm = (w >> 1) * (BM / 2), wn = (w & 1) * (BN / 2);
  const int lr = lane & 15, lg = lane >> 4;

  f32x4 acc[MT][NT];
  const f32x4 z4 = {0.f, 0.f, 0.f, 0.f};
#pragma unroll
  for (int m = 0; m < MT; ++m)
#pragma unroll
    for (int n = 0; n < NT; ++n) acc[m][n] = z4;

  auto stage = [&](int ks, int buf) {
    const int k0 = ks << 5;
#pragma unroll
    for (int i = 0; i < BM * 4 / 256; ++i) {
      const int o = i * 256 + tid;
      const int row = o >> 2, c = o & 3;
      gload_lds16(A + (size_t)(m0 + row) * K + k0 + c * 8, &As[buf][(i * 256 + w * 64) * 8]);
    }
#pragma unroll
    for (int i = 0; i < BN * 4 / 256; ++i) {
      const int o = i * 256 + tid;
      const int row = o >> 2, c = o & 3;
      gload_lds16(Bm + (size_t)(n0 + row) * K + k0 + c * 8, &Bs[buf][(i * 256 + w * 64) * 8]);
    }
  };

  const int nk = K >> 5;
  stage(0, 0);
  __syncthreads();
  for (int ks = 0; ks < nk; ++ks) {
    const int cur = ks & 1;
    if (ks + 1 < nk) stage(ks + 1, cur ^ 1);
    bf16x8 af[MT], bfr[NT];
#pragma unroll
    for (int m = 0; m < MT; ++m)
      af[m] = *(const bf16x8*)&As[cur][(wm + m * 16 + lr) * 32 + lg * 8];
#pragma unroll
    for (int n = 0; n < NT; ++n)
      bfr[n] = *(const bf16x8*)&Bs[cur][(wn + n * 16 + lr) * 32 + lg * 8];
    __builtin_amdgcn_s_setprio(1);
#pragma unroll
    for (int m = 0; m < MT; ++m)
#pragma unroll
      for (int n = 0; n < NT; ++n)
        acc[m][n] = __builtin_amdgcn_mfma_f32_16x16x32_bf16(af[m], bfr[n], acc[m][n], 0, 0, 0);
    __builtin_amdgcn_s_setprio(0);
    __syncthreads();
  }

#pragma unroll
  for (int n = 0; n < NT; ++n) {
    const int e = n0 + wn + n * 16 + lr;
    const float bv = bias[e];
    if (EPI == 1 && (e >> 10) == 2) {
      // V: write transposed [bh][d][s], 4 consecutive s packed per store
      const int h = (e >> 6) & 15, d = e & 63;
#pragma unroll
      for (int m = 0; m < MT; ++m) {
        const int row0 = m0 + wm + m * 16 + lg * 4;
        const int bb = row0 >> 11, s0 = row0 & 2047;
        uint2 pv;
        pv.x = cvtpk(acc[m][n][0] + bv, acc[m][n][1] + bv);
        pv.y = cvtpk(acc[m][n][2] + bv, acc[m][n][3] + bv);
        *(uint2*)(Vt + (size_t)(bb * 16 + h) * 131072 + (size_t)d * 2048 + s0) = pv;
      }
    } else {
#pragma unroll
      for (int m = 0; m < MT; ++m) {
#pragma unroll
        for (int r = 0; r < 4; ++r) {
          const int row = m0 + wm + m * 16 + lg * 4 + r;  // D: col=lane&15, row=(lane>>4)*4+r
          const float v = acc[m][n][r] + bv;
          if (EPI == 0) {
            ((float*)Cout)[(size_t)row * N + e] = v;
          } else {
            const int which = e >> 10, h = (e >> 6) & 15, d = e & 63;
            const int bb = row >> 11, s = row & 2047;
            ((u16*)Cout)[(size_t)which * 4194304 +
                         (((size_t)(bb * 16 + h) * 2048 + s) << 6) + d] = f2bf(v);
          }
        }
      }
    }
  }
}

// ---------------- fused attention: no LDS staging, no barriers ----------------
// grid: 1024 blocks (XCD-chunked) = bh(32) x qtile(32). 4 waves x 16 q-rows, free-running.
// K/V are L2-resident (262 KB/head): MFMA fragments load DIRECTLY from global.
// Fixed-M0 softmax (M0 = 8 post-scale): p = exp2(s*log2e/8 - 8*log2e); masked -> 0.
// Pass 1: per-lane l-sum only. Pass 2: recompute p, w = p/l, float4 weight stores,
// P->bf16 via cvt_pk through per-wave swizzled LDS into PV A-fragments.
__global__ __launch_bounds__(256, 4) void attn(const u16* __restrict__ Q,
                                               const u16* __restrict__ Kg,
                                               const u16* __restrict__ Vtg,
                                               const int* __restrict__ mask,
                                               float* __restrict__ Wout,
                                               u16* __restrict__ Og) {
  __shared__ u16 Pl[4][16 * 64];  // per-wave [16 q][64 t] bf16, XOR-swizzled
  const int L = ((int)blockIdx.x & 7) * 128 + ((int)blockIdx.x >> 3);  // XCD chunking
  const int bh = L >> 5, qt = L & 31;
  const int b = bh >> 4, h = bh & 15;
  const int tid = threadIdx.x;
  const int w = tid >> 6, lane = tid & 63;
  const int lr = lane & 15, lg = lane >> 4;
  const int srow0 = qt * 64 + w * 16;
  const float C2 = 0.18033688011112042f;  // log2(e)/8
  const float M2 = 11.541560327111707f;   // 8*log2(e)

  const u16* qrow = Q + ((size_t)bh * 2048 + srow0 + lr) * 64;
  const bf16x8 qf0 = *(const bf16x8*)(qrow + lg * 8);
  const bf16x8 qf1 = *(const bf16x8*)(qrow + 32 + lg * 8);
  const u16* kbase = Kg + (size_t)bh * 131072;   // [t][d]
  const u16* vbase = Vtg + (size_t)bh * 131072;  // [d][t]
  const int* mrow = mask + b * 2048;

  // pr[n][r] = unnormalized p for [q = srow0+lr][t = kt*64 + n*16 + lg*4 + r]
  auto probs = [&](int kt, f32x4* pr) {
    const u16* kt0 = kbase + (size_t)kt * 4096;
    __builtin_amdgcn_s_setprio(1);
#pragma unroll
    for (int n = 0; n < 4; ++n) {
      const u16* krow = kt0 + (n * 16 + lr) * 64;
      const bf16x8 k0 = *(const bf16x8*)(krow + lg * 8);
      const bf16x8 k1 = *(const bf16x8*)(krow + 32 + lg * 8);
      f32x4 s = {0.f, 0.f, 0.f, 0.f};
      s = __builtin_amdgcn_mfma_f32_16x16x32_bf16(k0, qf0, s, 0, 0, 0);
      s = __builtin_amdgcn_mfma_f32_16x16x32_bf16(k1, qf1, s, 0, 0, 0);
      const int4 mv = *(const int4*)&mrow[kt * 64 + n * 16 + lg * 4];
      f32x4 p;
      p[0] = (mv.x == 0) ? 0.f : fexp2(fmaf(s[0], C2, -M2));
      p[1] = (mv.y == 0) ? 0.f : fexp2(fmaf(s[1], C2, -M2));
      p[2] = (mv.z == 0) ? 0.f : fexp2(fmaf(s[2], C2, -M2));
      p[3] = (mv.w == 0) ? 0.f : fexp2(fmaf(s[3], C2, -M2));
      pr[n] = p;
    }
    __builtin_amdgcn_s_setprio(0);
  };

  // ---- pass 1: per-lane denominator ----
  float lsum = 0.f;
#pragma unroll 2
  for (int kt = 0; kt < 32; ++kt) {
    f32x4 pr[4];
    probs(kt, pr);
    float s0 = pr[0][0] + pr[0][1] + pr[0][2] + pr[0][3];
    float s1 = pr[1][0] + pr[1][1] + pr[1][2] + pr[1][3];
    float s2 = pr[2][0] + pr[2][1] + pr[2][2] + pr[2][3];
    float s3 = pr[3][0] + pr[3][1] + pr[3][2] + pr[3][3];
    lsum += (s0 + s1) + (s2 + s3);
  }
  lsum += __shfl_xor(lsum, 16);
  lsum += __shfl_xor(lsum, 32);
  const float rl = 1.0f / lsum;

  // ---- pass 2: weights + PV ----
  f32x4 oacc[4];
  const f32x4 z4 = {0.f, 0.f, 0.f, 0.f};
#pragma unroll
  for (int n = 0; n < 4; ++n) oacc[n] = z4;

  float* wrow = Wout + ((size_t)bh * 2048 + srow0 + lr) * 2048;  // per-lane q-row
  char* plw = (char*)&Pl[w][0];
  const int pswz = (lr & 3) << 5;

  for (int kt = 0; kt < 32; ++kt) {
    f32x4 pr[4];
    probs(kt, pr);
#pragma unroll
    for (int n = 0; n < 4; ++n) {
      f32x4 wv;
      wv[0] = pr[n][0] * rl;
      wv[1] = pr[n][1] * rl;
      wv[2] = pr[n][2] * rl;
      wv[3] = pr[n][3] * rl;
      *(f32x4*)&wrow[kt * 64 + n * 16 + lg * 4] = wv;  // float4 weight store
      uint2 pw;
      pw.x = cvtpk(wv[0], wv[1]);
      pw.y = cvtpk(wv[2], wv[3]);
      *(uint2*)(plw + (lr * 128 + ((n * 32 + lg * 8) ^ pswz))) = pw;
    }
    const bf16x8 pf0 = *(const bf16x8*)(plw + (lr * 128 + ((lg * 16) ^ pswz)));
    const bf16x8 pf1 = *(const bf16x8*)(plw + (lr * 128 + ((64 + lg * 16) ^ pswz)));
    __builtin_amdgcn_s_setprio(1);
#pragma unroll
    for (int n = 0; n < 4; ++n) {
      const u16* vrow = vbase + (size_t)(n * 16 + lr) * 2048 + kt * 64;
      const bf16x8 v0 = *(const bf16x8*)(vrow + lg * 8);
      const bf16x8 v1 = *(const bf16x8*)(vrow + 32 + lg * 8);
      oacc[n] = __builtin_amdgcn_mfma_f32_16x16x32_bf16(pf0, v0, oacc[n], 0, 0, 0);
      oacc[n] = __builtin_amdgcn_mfma_f32_16x16x32_bf16(pf1, v1, oacc[n], 0, 0, 0);
    }
    __builtin_amdgcn_s_setprio(0);
  }

  // O: lane holds O[q = srow0 + lg*4 + r][d = n*16 + lr]
#pragma unroll
  for (int n = 0; n < 4; ++n) {
#pragma unroll
    for (int r = 0; r < 4; ++r) {
      const int s = srow0 + lg * 4 + r;
      Og[((size_t)(b * 2048 + s)) * 1024 + h * 64 + n * 16 + lr] = f2bf(oacc[n][r]);
    }
  }
}

// ---------------- launch ----------------
extern "C" void kernel_launch(void* const* d_in, const int* in_sizes, int n_in,
                              void* d_out, int out_size, void* d_ws, size_t ws_size,
                              hipStream_t stream) {
  const float* x     = (const float*)d_in[0];
  const int*   mask  = (const int*)d_in[1];
  const float* qkv_w = (const float*)d_in[2];
  const float* qkv_b = (const float*)d_in[3];
  const float* wo_w  = (const float*)d_in[4];
  const float* wo_b  = (const float*)d_in[5];
  float* out = (float*)d_out;

  char* ws = (char*)d_ws;
  u16* xb   = (u16*)(ws);                          // 4096x1024
  u16* qwb  = (u16*)(ws + (8u << 20));             // 3072x1024
  u16* wob  = (u16*)(ws + (14u << 20));            // 1024x1024
  u16* qkvb = (u16*)(ws + (16u << 20));            // Q,K: [bh][s][64] bf16 (V slot unused)
  u16* vt   = (u16*)(ws + (40u << 20));            // [bh][64][2048] bf16 (written by QKV epi)
  u16* ob   = (u16*)(ws + (48u << 20));            // attn out [4096][1024] bf16

  cvt3<<<8192, 256, 0, stream>>>(x, xb, qkv_w, qwb, wo_w, wob);
  gemm_bt<1, 128, 128><<<768, 256, 0, stream>>>(xb, qwb, qkv_b, qkvb, vt, 4096, 3072, 1024);
  attn<<<1024, 256, 0, stream>>>(qkvb, qkvb + 4194304, vt, mask, out + 4194304, ob);
  gemm_bt<0, 128, 64><<<512, 256, 0, stream>>>(ob, wob, wo_b, out, nullptr, 4096, 1024, 1024);
}

// Round 4
// 480.349 us; speedup vs baseline: 1.0075x; 1.0075x over previous
//
#include <hip/hip_runtime.h>
#include <cstdint>
#include <cstddef>

typedef unsigned short u16;
typedef __attribute__((ext_vector_type(8))) short bf16x8;
typedef __attribute__((ext_vector_type(4))) float f32x4;

#define DEV static __device__ __forceinline__

DEV void gload_lds16(const void* g, void* l) {
  __builtin_amdgcn_global_load_lds((const __attribute__((address_space(1))) void*)g,
                                   (__attribute__((address_space(3))) void*)l, 16, 0, 0);
}

DEV u16 f2bf(float f) {  // RNE fp32 -> bf16 (finite inputs)
  unsigned x = __float_as_uint(f);
  return (u16)((x + 0x7FFFu + ((x >> 16) & 1u)) >> 16);
}

DEV unsigned cvtpk(float lo, float hi) {  // bf16(lo) in [15:0], bf16(hi) in [31:16]
  unsigned r;
  asm("v_cvt_pk_bf16_f32 %0, %1, %2" : "=v"(r) : "v"(lo), "v"(hi));
  return r;
}

#if __has_builtin(__builtin_amdgcn_exp2f)
DEV float fexp2(float x) { return __builtin_amdgcn_exp2f(x); }
#else
DEV float fexp2(float x) { return exp2f(x); }
#endif

// ---------------- fp32 -> bf16 convert, 3 buffers in one launch ----------------
__global__ __launch_bounds__(256) void cvt3(const float* __restrict__ a, u16* __restrict__ da,
                                            const float* __restrict__ b, u16* __restrict__ db,
                                            const float* __restrict__ c, u16* __restrict__ dc) {
  int bid = blockIdx.x;
  const float* s;
  u16* d;
  int base;
  if (bid < 4096) { s = a; d = da; base = bid; }
  else if (bid < 7168) { s = b; d = db; base = bid - 4096; }
  else { s = c; d = dc; base = bid - 7168; }
  const int i = (base * 256 + (int)threadIdx.x) * 4;
  float4 v = *(const float4*)(s + i);
  uint2 p;
  p.x = (unsigned)f2bf(v.x) | ((unsigned)f2bf(v.y) << 16);
  p.y = (unsigned)f2bf(v.z) | ((unsigned)f2bf(v.w) << 16);
  *(uint2*)(d + i) = p;
}

// ---------------- GEMM: C = A * B^T (+bias) ----------------
// A[M][K] bf16 row-major, Bm[N][K] bf16 row-major.
// EPI 0: Cout = float[M][N], v + bias[e]
// EPI 1: QKV scatter: Q,K -> [which][b*16+h][s][d] bf16; V -> Vt[b*16+h][d][s] (transposed)
template <int EPI, int BM, int BN>
__global__ __launch_bounds__(256) void gemm_bt(const u16* __restrict__ A,
                                               const u16* __restrict__ Bm,
                                               const float* __restrict__ bias,
                                               void* __restrict__ Cout,
                                               u16* __restrict__ Vt,
                                               int M, int N, int K) {
  __shared__ u16 As[2][BM * 32];
  __shared__ u16 Bs[2][BN * 32];
  constexpr int MT = BM / 32, NT = BN / 32;
  const int cpx = (int)gridDim.x >> 3;
  const int bid = ((int)blockIdx.x & 7) * cpx + ((int)blockIdx.x >> 3);  // XCD chunking
  const int nb = N / BN;
  const int m0 = (bid / nb) * BM;
  const int n0 = (bid % nb) * BN;
  const int tid = threadIdx.x;
  const int w = tid >> 6, lane = tid & 63;
  const int wm = (w >> 1) * (BM / 2), wn = (w & 1) * (BN / 2);
  const int lr = lane & 15, lg = lane >> 4;

  f32x4 acc[MT][NT];
  const f32x4 z4 = {0.f, 0.f, 0.f, 0.f};
#pragma unroll
  for (int m = 0; m < MT; ++m)
#pragma unroll
    for (int n = 0; n < NT; ++n) acc[m][n] = z4;

  auto stage = [&](int ks, int buf) {
    const int k0 = ks << 5;
#pragma unroll
    for (int i = 0; i < BM * 4 / 256; ++i) {
      const int o = i * 256 + tid;
      const int row = o >> 2, c = o & 3;
      gload_lds16(A + (size_t)(m0 + row) * K + k0 + c * 8, &As[buf][(i * 256 + w * 64) * 8]);
    }
#pragma unroll
    for (int i = 0; i < BN * 4 / 256; ++i) {
      const int o = i * 256 + tid;
      const int row = o >> 2, c = o & 3;
      gload_lds16(Bm + (size_t)(n0 + row) * K + k0 + c * 8, &Bs[buf][(i * 256 + w * 64) * 8]);
    }
  };

  const int nk = K >> 5;
  stage(0, 0);
  __syncthreads();
  for (int ks = 0; ks < nk; ++ks) {
    const int cur = ks & 1;
    if (ks + 1 < nk) stage(ks + 1, cur ^ 1);
    bf16x8 af[MT], bfr[NT];
#pragma unroll
    for (int m = 0; m < MT; ++m)
      af[m] = *(const bf16x8*)&As[cur][(wm + m * 16 + lr) * 32 + lg * 8];
#pragma unroll
    for (int n = 0; n < NT; ++n)
      bfr[n] = *(const bf16x8*)&Bs[cur][(wn + n * 16 + lr) * 32 + lg * 8];
    __builtin_amdgcn_s_setprio(1);
#pragma unroll
    for (int m = 0; m < MT; ++m)
#pragma unroll
      for (int n = 0; n < NT; ++n)
        acc[m][n] = __builtin_amdgcn_mfma_f32_16x16x32_bf16(af[m], bfr[n], acc[m][n], 0, 0, 0);
    __builtin_amdgcn_s_setprio(0);
    __syncthreads();
  }

#pragma unroll
  for (int n = 0; n < NT; ++n) {
    const int e = n0 + wn + n * 16 + lr;
    const float bv = bias[e];
    if (EPI == 1 && (e >> 10) == 2) {
      // V: write transposed [bh][d][s], 4 consecutive s packed per store
      const int h = (e >> 6) & 15, d = e & 63;
#pragma unroll
      for (int m = 0; m < MT; ++m) {
        const int row0 = m0 + wm + m * 16 + lg * 4;
        const int bb = row0 >> 11, s0 = row0 & 2047;
        uint2 pv;
        pv.x = cvtpk(acc[m][n][0] + bv, acc[m][n][1] + bv);
        pv.y = cvtpk(acc[m][n][2] + bv, acc[m][n][3] + bv);
        *(uint2*)(Vt + (size_t)(bb * 16 + h) * 131072 + (size_t)d * 2048 + s0) = pv;
      }
    } else {
#pragma unroll
      for (int m = 0; m < MT; ++m) {
#pragma unroll
        for (int r = 0; r < 4; ++r) {
          const int row = m0 + wm + m * 16 + lg * 4 + r;  // D: col=lane&15, row=(lane>>4)*4+r
          const float v = acc[m][n][r] + bv;
          if (EPI == 0) {
            ((float*)Cout)[(size_t)row * N + e] = v;
          } else {
            const int which = e >> 10, h = (e >> 6) & 15, d = e & 63;
            const int bb = row >> 11, s = row & 2047;
            ((u16*)Cout)[(size_t)which * 4194304 +
                         (((size_t)(bb * 16 + h) * 2048 + s) << 6) + d] = f2bf(v);
          }
        }
      }
    }
  }
}

// ---------------- fused attention: barrier-free, register-pipelined ----------------
// grid: 1024 blocks (XCD-chunked) = bh(32) x qtile(32). 4 waves x 16 q-rows, free-running.
// K/V are L2-resident; fragments load directly from global BUT with explicit depth-1
// register double-buffering (kA/kB) so every load has a full body (~500 cyc) of lead.
// V fragments issue at body top, consumed after softmax (~300 cyc lead).
// Fixed-M0 softmax: p = exp2(s*log2e/8 - 8*log2e); masked -> 0.
__global__ __launch_bounds__(256, 3) void attn(const u16* __restrict__ Q,
                                               const u16* __restrict__ Kg,
                                               const u16* __restrict__ Vtg,
                                               const int* __restrict__ mask,
                                               float* __restrict__ Wout,
                                               u16* __restrict__ Og) {
  __shared__ u16 Pl[4][16 * 64];  // per-wave [16 q][64 t] bf16, XOR-swizzled (lr&7)<<4
  const int L = ((int)blockIdx.x & 7) * 128 + ((int)blockIdx.x >> 3);  // XCD chunking
  const int bh = L >> 5, qt = L & 31;
  const int b = bh >> 4, h = bh & 15;
  const int tid = threadIdx.x;
  const int w = tid >> 6, lane = tid & 63;
  const int lr = lane & 15, lg = lane >> 4;
  const int srow0 = qt * 64 + w * 16;
  const float C2 = 0.18033688011112042f;  // log2(e)/8
  const float M2 = 11.541560327111707f;   // 8*log2(e)

  const u16* qrow = Q + ((size_t)bh * 2048 + srow0 + lr) * 64;
  const bf16x8 qf0 = *(const bf16x8*)(qrow + lg * 8);
  const bf16x8 qf1 = *(const bf16x8*)(qrow + 32 + lg * 8);
  const u16* kbase = Kg + (size_t)bh * 131072;   // [t][d]
  const u16* vbase = Vtg + (size_t)bh * 131072;  // [d][t]
  const int* mrow = mask + b * 2048;

  auto loadK = [&](int kt, bf16x8* kf) {
    const u16* kt0 = kbase + (size_t)kt * 4096;
#pragma unroll
    for (int n = 0; n < 4; ++n) {
      const u16* krow = kt0 + (n * 16 + lr) * 64;
      kf[2 * n] = *(const bf16x8*)(krow + lg * 8);
      kf[2 * n + 1] = *(const bf16x8*)(krow + 32 + lg * 8);
    }
  };
  auto loadV = [&](int kt, bf16x8* vf) {
#pragma unroll
    for (int n = 0; n < 4; ++n) {
      const u16* vrow = vbase + (size_t)(n * 16 + lr) * 2048 + kt * 64;
      vf[2 * n] = *(const bf16x8*)(vrow + lg * 8);
      vf[2 * n + 1] = *(const bf16x8*)(vrow + 32 + lg * 8);
    }
  };
  // p[n] for [q=srow0+lr][t = kt*64 + n*16 + lg*4 + r] from resident K frags
  auto probs = [&](int kt, const bf16x8* kf, f32x4* pr) {
    int4 mv[4];
#pragma unroll
    for (int n = 0; n < 4; ++n) mv[n] = *(const int4*)&mrow[kt * 64 + n * 16 + lg * 4];
    f32x4 sc[4];
    __builtin_amdgcn_s_setprio(1);
#pragma unroll
    for (int n = 0; n < 4; ++n) {
      f32x4 s = {0.f, 0.f, 0.f, 0.f};
      s = __builtin_amdgcn_mfma_f32_16x16x32_bf16(kf[2 * n], qf0, s, 0, 0, 0);
      s = __builtin_amdgcn_mfma_f32_16x16x32_bf16(kf[2 * n + 1], qf1, s, 0, 0, 0);
      sc[n] = s;
    }
    __builtin_amdgcn_s_setprio(0);
#pragma unroll
    for (int n = 0; n < 4; ++n) {
      f32x4 p;
      p[0] = (mv[n].x == 0) ? 0.f : fexp2(fmaf(sc[n][0], C2, -M2));
      p[1] = (mv[n].y == 0) ? 0.f : fexp2(fmaf(sc[n][1], C2, -M2));
      p[2] = (mv[n].z == 0) ? 0.f : fexp2(fmaf(sc[n][2], C2, -M2));
      p[3] = (mv[n].w == 0) ? 0.f : fexp2(fmaf(sc[n][3], C2, -M2));
      pr[n] = p;
    }
  };

  bf16x8 kA[8], kB[8], vA[8];

  // ---- pass 1: per-lane denominator (K reg-double-buffered, zero barriers) ----
  float lsum = 0.f;
  loadK(0, kA);
  auto psum = [&](int kt, const bf16x8* kf) {
    f32x4 pr[4];
    probs(kt, kf, pr);
    float s0 = (pr[0][0] + pr[0][1]) + (pr[0][2] + pr[0][3]);
    float s1 = (pr[1][0] + pr[1][1]) + (pr[1][2] + pr[1][3]);
    float s2 = (pr[2][0] + pr[2][1]) + (pr[2][2] + pr[2][3]);
    float s3 = (pr[3][0] + pr[3][1]) + (pr[3][2] + pr[3][3]);
    lsum += (s0 + s1) + (s2 + s3);
  };
  for (int kt = 0; kt < 32; kt += 2) {
    loadK(kt + 1, kB);
    psum(kt, kA);
    loadK(kt + 2, kA);  // kt=30 -> reads tile 32 (unused V slot, safe)
    psum(kt + 1, kB);
  }
  lsum += __shfl_xor(lsum, 16);
  lsum += __shfl_xor(lsum, 32);
  const float rl = 1.0f / lsum;

  // ---- pass 2: weights + PV ----
  f32x4 oacc[4];
  const f32x4 z4 = {0.f, 0.f, 0.f, 0.f};
#pragma unroll
  for (int n = 0; n < 4; ++n) oacc[n] = z4;

  float* wrow = Wout + ((size_t)bh * 2048 + srow0 + lr) * 2048;  // per-lane q-row
  char* plw = (char*)&Pl[w][0];
  const int pswz = (lr & 7) << 4;  // canonical Guideline-4 swizzle

  auto body = [&](int kt, const bf16x8* kf) {
    f32x4 pr[4];
    probs(kt, kf, pr);
#pragma unroll
    for (int n = 0; n < 4; ++n) {
      f32x4 wv;
      wv[0] = pr[n][0] * rl;
      wv[1] = pr[n][1] * rl;
      wv[2] = pr[n][2] * rl;
      wv[3] = pr[n][3] * rl;
      *(f32x4*)&wrow[kt * 64 + n * 16 + lg * 4] = wv;  // float4 weight store
      uint2 pw;
      pw.x = cvtpk(wv[0], wv[1]);
      pw.y = cvtpk(wv[2], wv[3]);
      *(uint2*)(plw + (lr * 128 + ((n * 32 + lg * 8) ^ pswz))) = pw;
    }
    const bf16x8 pf0 = *(const bf16x8*)(plw + (lr * 128 + ((lg * 16) ^ pswz)));
    const bf16x8 pf1 = *(const bf16x8*)(plw + (lr * 128 + ((64 + lg * 16) ^ pswz)));
    __builtin_amdgcn_s_setprio(1);
#pragma unroll
    for (int n = 0; n < 4; ++n) {
      oacc[n] = __builtin_amdgcn_mfma_f32_16x16x32_bf16(pf0, vA[2 * n], oacc[n], 0, 0, 0);
      oacc[n] = __builtin_amdgcn_mfma_f32_16x16x32_bf16(pf1, vA[2 * n + 1], oacc[n], 0, 0, 0);
    }
    __builtin_amdgcn_s_setprio(0);
  };

  loadK(0, kA);
  for (int kt = 0; kt < 32; kt += 2) {
    loadK(kt + 1, kB);
    loadV(kt, vA);
    body(kt, kA);
    loadK(kt + 2, kA);  // tile 32 read is benign
    loadV(kt + 1, vA);
    body(kt + 1, kB);
  }

  // O: lane holds O[q = srow0 + lg*4 + r][d = n*16 + lr]
#pragma unroll
  for (int n = 0; n < 4; ++n) {
#pragma unroll
    for (int r = 0; r < 4; ++r) {
      const int s = srow0 + lg * 4 + r;
      Og[((size_t)(b * 2048 + s)) * 1024 + h * 64 + n * 16 + lr] = f2bf(oacc[n][r]);
    }
  }
}

// ---------------- launch ----------------
extern "C" void kernel_launch(void* const* d_in, const int* in_sizes, int n_in,
                              void* d_out, int out_size, void* d_ws, size_t ws_size,
                              hipStream_t stream) {
  const float* x     = (const float*)d_in[0];
  const int*   mask  = (const int*)d_in[1];
  const float* qkv_w = (const float*)d_in[2];
  const float* qkv_b = (const float*)d_in[3];
  const float* wo_w  = (const float*)d_in[4];
  const float* wo_b  = (const float*)d_in[5];
  float* out = (float*)d_out;

  char* ws = (char*)d_ws;
  u16* xb   = (u16*)(ws);                          // 4096x1024
  u16* qwb  = (u16*)(ws + (8u << 20));             // 3072x1024
  u16* wob  = (u16*)(ws + (14u << 20));            // 1024x1024
  u16* qkvb = (u16*)(ws + (16u << 20));            // Q,K: [bh][s][64] bf16 (V slot = overrun pad)
  u16* vt   = (u16*)(ws + (40u << 20));            // [bh][64][2048] bf16 (written by QKV epi)
  u16* ob   = (u16*)(ws + (48u << 20));            // attn out [4096][1024] bf16

  cvt3<<<8192, 256, 0, stream>>>(x, xb, qkv_w, qwb, wo_w, wob);
  gemm_bt<1, 128, 128><<<768, 256, 0, stream>>>(xb, qwb, qkv_b, qkvb, vt, 4096, 3072, 1024);
  attn<<<1024, 256, 0, stream>>>(qkvb, qkvb + 4194304, vt, mask, out + 4194304, ob);
  gemm_bt<0, 128, 64><<<512, 256, 0, stream>>>(ob, wob, wo_b, out, nullptr, 4096, 1024, 1024);
}

// Round 5
// 260.849 us; speedup vs baseline: 1.8553x; 1.8415x over previous
//
#include <hip/hip_runtime.h>
#include <cstdint>
#include <cstddef>

typedef unsigned short u16;
typedef __attribute__((ext_vector_type(8))) short bf16x8;
typedef __attribute__((ext_vector_type(4))) float f32x4;

#define DEV static __device__ __forceinline__

DEV void gload_lds16(const void* g, void* l) {
  __builtin_amdgcn_global_load_lds((const __attribute__((address_space(1))) void*)g,
                                   (__attribute__((address_space(3))) void*)l, 16, 0, 0);
}

DEV u16 f2bf(float f) {  // RNE fp32 -> bf16 (finite inputs)
  unsigned x = __float_as_uint(f);
  return (u16)((x + 0x7FFFu + ((x >> 16) & 1u)) >> 16);
}

DEV unsigned cvtpk(float lo, float hi) {  // bf16(lo) in [15:0], bf16(hi) in [31:16]
  unsigned r;
  asm("v_cvt_pk_bf16_f32 %0, %1, %2" : "=v"(r) : "v"(lo), "v"(hi));
  return r;
}

#if __has_builtin(__builtin_amdgcn_exp2f)
DEV float fexp2(float x) { return __builtin_amdgcn_exp2f(x); }
#else
DEV float fexp2(float x) { return exp2f(x); }
#endif

// ---------------- fp32 -> bf16 convert, 3 buffers in one launch ----------------
__global__ __launch_bounds__(256) void cvt3(const float* __restrict__ a, u16* __restrict__ da,
                                            const float* __restrict__ b, u16* __restrict__ db,
                                            const float* __restrict__ c, u16* __restrict__ dc) {
  int bid = blockIdx.x;
  const float* s;
  u16* d;
  int base;
  if (bid < 4096) { s = a; d = da; base = bid; }
  else if (bid < 7168) { s = b; d = db; base = bid - 4096; }
  else { s = c; d = dc; base = bid - 7168; }
  const int i = (base * 256 + (int)threadIdx.x) * 4;
  float4 v = *(const float4*)(s + i);
  uint2 p;
  p.x = (unsigned)f2bf(v.x) | ((unsigned)f2bf(v.y) << 16);
  p.y = (unsigned)f2bf(v.z) | ((unsigned)f2bf(v.w) << 16);
  *(uint2*)(d + i) = p;
}

// ---------------- GEMM: C = A * B^T (+bias) ----------------
// A[M][K] bf16 row-major, Bm[N][K] bf16 row-major.
// EPI 0: Cout = float[M][N], v + bias[e]
// EPI 1: QKV scatter: Q,K -> [which][b*16+h][s][d] bf16; V -> Vt[b*16+h][d][s] (transposed)
template <int EPI, int BM, int BN>
__global__ __launch_bounds__(256) void gemm_bt(const u16* __restrict__ A,
                                               const u16* __restrict__ Bm,
                                               const float* __restrict__ bias,
                                               void* __restrict__ Cout,
                                               u16* __restrict__ Vt,
                                               int M, int N, int K) {
  __shared__ u16 As[2][BM * 32];
  __shared__ u16 Bs[2][BN * 32];
  constexpr int MT = BM / 32, NT = BN / 32;
  const int cpx = (int)gridDim.x >> 3;
  const int bid = ((int)blockIdx.x & 7) * cpx + ((int)blockIdx.x >> 3);  // XCD chunking
  const int nb = N / BN;
  const int m0 = (bid / nb) * BM;
  const int n0 = (bid % nb) * BN;
  const int tid = threadIdx.x;
  const int w = tid >> 6, lane = tid & 63;
  const int wm = (w >> 1) * (BM / 2), wn = (w & 1) * (BN / 2);
  const int lr = lane & 15, lg = lane >> 4;

  f32x4 acc[MT][NT];
  const f32x4 z4 = {0.f, 0.f, 0.f, 0.f};
#pragma unroll
  for (int m = 0; m < MT; ++m)
#pragma unroll
    for (int n = 0; n < NT; ++n) acc[m][n] = z4;

  auto stage = [&](int ks, int buf) {
    const int k0 = ks << 5;
#pragma unroll
    for (int i = 0; i < BM * 4 / 256; ++i) {
      const int o = i * 256 + tid;
      const int row = o >> 2, c = o & 3;
      gload_lds16(A + (size_t)(m0 + row) * K + k0 + c * 8, &As[buf][(i * 256 + w * 64) * 8]);
    }
#pragma unroll
    for (int i = 0; i < BN * 4 / 256; ++i) {
      const int o = i * 256 + tid;
      const int row = o >> 2, c = o & 3;
      gload_lds16(Bm + (size_t)(n0 + row) * K + k0 + c * 8, &Bs[buf][(i * 256 + w * 64) * 8]);
    }
  };

  const int nk = K >> 5;
  stage(0, 0);
  __syncthreads();
  for (int ks = 0; ks < nk; ++ks) {
    const int cur = ks & 1;
    if (ks + 1 < nk) stage(ks + 1, cur ^ 1);
    bf16x8 af[MT], bfr[NT];
#pragma unroll
    for (int m = 0; m < MT; ++m)
      af[m] = *(const bf16x8*)&As[cur][(wm + m * 16 + lr) * 32 + lg * 8];
#pragma unroll
    for (int n = 0; n < NT; ++n)
      bfr[n] = *(const bf16x8*)&Bs[cur][(wn + n * 16 + lr) * 32 + lg * 8];
    __builtin_amdgcn_s_setprio(1);
#pragma unroll
    for (int m = 0; m < MT; ++m)
#pragma unroll
      for (int n = 0; n < NT; ++n)
        acc[m][n] = __builtin_amdgcn_mfma_f32_16x16x32_bf16(af[m], bfr[n], acc[m][n], 0, 0, 0);
    __builtin_amdgcn_s_setprio(0);
    __syncthreads();
  }

#pragma unroll
  for (int n = 0; n < NT; ++n) {
    const int e = n0 + wn + n * 16 + lr;
    const float bv = bias[e];
    if (EPI == 1 && (e >> 10) == 2) {
      // V: write transposed [bh][d][s], 4 consecutive s packed per store
      const int h = (e >> 6) & 15, d = e & 63;
#pragma unroll
      for (int m = 0; m < MT; ++m) {
        const int row0 = m0 + wm + m * 16 + lg * 4;
        const int bb = row0 >> 11, s0 = row0 & 2047;
        uint2 pv;
        pv.x = cvtpk(acc[m][n][0] + bv, acc[m][n][1] + bv);
        pv.y = cvtpk(acc[m][n][2] + bv, acc[m][n][3] + bv);
        *(uint2*)(Vt + (size_t)(bb * 16 + h) * 131072 + (size_t)d * 2048 + s0) = pv;
      }
    } else {
#pragma unroll
      for (int m = 0; m < MT; ++m) {
#pragma unroll
        for (int r = 0; r < 4; ++r) {
          const int row = m0 + wm + m * 16 + lg * 4 + r;  // D: col=lane&15, row=(lane>>4)*4+r
          const float v = acc[m][n][r] + bv;
          if (EPI == 0) {
            ((float*)Cout)[(size_t)row * N + e] = v;
          } else {
            const int which = e >> 10, h = (e >> 6) & 15, d = e & 63;
            const int bb = row >> 11, s = row & 2047;
            ((u16*)Cout)[(size_t)which * 4194304 +
                         (((size_t)(bb * 16 + h) * 2048 + s) << 6) + d] = f2bf(v);
          }
        }
      }
    }
  }
}

// ---------------- fused attention: LDS-staged (coalesced), fixed-M0 softmax ----------------
// grid: 1024 blocks (XCD-chunked) = bh(32) x qtile(32). 4 waves x 16 q-rows.
// K/V staged via global_load_lds (coalesced dwordx4), double-buffered, 1 barrier/tile.
// Swapped QK^T: lane owns one q-row (q = lane&15); fixed-M0 softmax:
// p = exp2(s*log2e/8 - 8*log2e); masked -> 0. Pass 1: per-lane l-sum (K only).
// Pass 2: recompute p, w = p*rl float4 stores, p->bf16 via cvt_pk through per-wave
// swizzled LDS into PV A-fragments; V from transposed Vt tiles.
__global__ __launch_bounds__(256) void attn(const u16* __restrict__ Q,
                                            const u16* __restrict__ Kg,
                                            const u16* __restrict__ Vtg,
                                            const int* __restrict__ mask,
                                            float* __restrict__ Wout,
                                            u16* __restrict__ Og) {
  __shared__ u16 Ks[2][64 * 64];
  __shared__ u16 Vs[2][64 * 64];
  __shared__ u16 Pl[4][16 * 64];  // per-wave [16 q][64 t] bf16, XOR-swizzled (lr&7)<<4
  const int L = ((int)blockIdx.x & 7) * 128 + ((int)blockIdx.x >> 3);  // XCD chunking
  const int bh = L >> 5, qt = L & 31;
  const int b = bh >> 4, h = bh & 15;
  const int tid = threadIdx.x;
  const int w = tid >> 6, lane = tid & 63;
  const int lr = lane & 15, lg = lane >> 4;
  const int srow0 = qt * 64 + w * 16;
  const float C2 = 0.18033688011112042f;  // log2(e)/8
  const float M2 = 11.541560327111707f;   // 8*log2(e)

  const u16* qrow = Q + ((size_t)bh * 2048 + srow0 + lr) * 64;
  const bf16x8 qf0 = *(const bf16x8*)(qrow + lg * 8);
  const bf16x8 qf1 = *(const bf16x8*)(qrow + 32 + lg * 8);
  const int* mrow = mask + b * 2048;

  auto stageK = [&](int kt, int buf) {
    const u16* g = Kg + (size_t)bh * 131072 + (size_t)kt * 4096;
#pragma unroll
    for (int iss = 0; iss < 2; ++iss) {
      const int o = iss * 256 + tid;
      const int row = o >> 3, c = o & 7;  // pre-swizzled global source, linear LDS dest
      gload_lds16(g + row * 64 + ((c ^ (row & 7)) << 3), &Ks[buf][(iss * 256 + w * 64) * 8]);
    }
  };
  auto stageV = [&](int kt, int buf) {
    const u16* g = Vtg + (size_t)bh * 131072 + kt * 64;  // [d][t] rows, stride 2048
#pragma unroll
    for (int iss = 0; iss < 2; ++iss) {
      const int o = iss * 256 + tid;
      const int row = o >> 3, c = o & 7;
      gload_lds16(g + (size_t)row * 2048 + ((c ^ (row & 7)) << 3),
                  &Vs[buf][(iss * 256 + w * 64) * 8]);
    }
  };
  // pr[n][r] = unnormalized p for [q = srow0+lr][t = kt*64 + n*16 + lg*4 + r]
  auto probs = [&](int cur, int kt, f32x4* pr) {
    int4 mv[4];
#pragma unroll
    for (int n = 0; n < 4; ++n) mv[n] = *(const int4*)&mrow[kt * 64 + n * 16 + lg * 4];
    f32x4 sc[4];
    __builtin_amdgcn_s_setprio(1);
#pragma unroll
    for (int n = 0; n < 4; ++n) {
      const int tr = n * 16 + lr;
      const bf16x8 k0 = *(const bf16x8*)&Ks[cur][tr * 64 + ((lg ^ (tr & 7)) << 3)];
      const bf16x8 k1 = *(const bf16x8*)&Ks[cur][tr * 64 + (((lg + 4) ^ (tr & 7)) << 3)];
      f32x4 s = {0.f, 0.f, 0.f, 0.f};
      s = __builtin_amdgcn_mfma_f32_16x16x32_bf16(k0, qf0, s, 0, 0, 0);
      s = __builtin_amdgcn_mfma_f32_16x16x32_bf16(k1, qf1, s, 0, 0, 0);
      sc[n] = s;
    }
    __builtin_amdgcn_s_setprio(0);
#pragma unroll
    for (int n = 0; n < 4; ++n) {
      f32x4 p;
      p[0] = (mv[n].x == 0) ? 0.f : fexp2(fmaf(sc[n][0], C2, -M2));
      p[1] = (mv[n].y == 0) ? 0.f : fexp2(fmaf(sc[n][1], C2, -M2));
      p[2] = (mv[n].z == 0) ? 0.f : fexp2(fmaf(sc[n][2], C2, -M2));
      p[3] = (mv[n].w == 0) ? 0.f : fexp2(fmaf(sc[n][3], C2, -M2));
      pr[n] = p;
    }
  };

  // ---- pass 1: per-lane denominator (K staged only) ----
  float lsum = 0.f;
  stageK(0, 0);
  __syncthreads();
  for (int kt = 0; kt < 32; ++kt) {
    const int cur = kt & 1;
    if (kt + 1 < 32) stageK(kt + 1, cur ^ 1);
    f32x4 pr[4];
    probs(cur, kt, pr);
    float s0 = (pr[0][0] + pr[0][1]) + (pr[0][2] + pr[0][3]);
    float s1 = (pr[1][0] + pr[1][1]) + (pr[1][2] + pr[1][3]);
    float s2 = (pr[2][0] + pr[2][1]) + (pr[2][2] + pr[2][3]);
    float s3 = (pr[3][0] + pr[3][1]) + (pr[3][2] + pr[3][3]);
    lsum += (s0 + s1) + (s2 + s3);
    __syncthreads();
  }
  lsum += __shfl_xor(lsum, 16);
  lsum += __shfl_xor(lsum, 32);
  const float rl = 1.0f / lsum;

  // ---- pass 2: weights + PV ----
  f32x4 oacc[4];
  const f32x4 z4 = {0.f, 0.f, 0.f, 0.f};
#pragma unroll
  for (int n = 0; n < 4; ++n) oacc[n] = z4;

  float* wrow = Wout + ((size_t)bh * 2048 + srow0 + lr) * 2048;  // per-lane q-row
  char* plw = (char*)&Pl[w][0];
  const int pswz = (lr & 7) << 4;

  stageK(0, 0);
  stageV(0, 0);
  __syncthreads();
  for (int kt = 0; kt < 32; ++kt) {
    const int cur = kt & 1;
    if (kt + 1 < 32) { stageK(kt + 1, cur ^ 1); stageV(kt + 1, cur ^ 1); }
    f32x4 pr[4];
    probs(cur, kt, pr);
#pragma unroll
    for (int n = 0; n < 4; ++n) {
      f32x4 wv;
      wv[0] = pr[n][0] * rl;
      wv[1] = pr[n][1] * rl;
      wv[2] = pr[n][2] * rl;
      wv[3] = pr[n][3] * rl;
      *(f32x4*)&wrow[kt * 64 + n * 16 + lg * 4] = wv;  // float4 weight store
      uint2 pw;
      pw.x = cvtpk(wv[0], wv[1]);
      pw.y = cvtpk(wv[2], wv[3]);
      *(uint2*)(plw + (lr * 128 + ((n * 32 + lg * 8) ^ pswz))) = pw;
    }
    const bf16x8 pf0 = *(const bf16x8*)(plw + (lr * 128 + ((lg * 16) ^ pswz)));
    const bf16x8 pf1 = *(const bf16x8*)(plw + (lr * 128 + ((64 + lg * 16) ^ pswz)));
    __builtin_amdgcn_s_setprio(1);
#pragma unroll
    for (int n = 0; n < 4; ++n) {
      const int dr = n * 16 + lr;
      const bf16x8 v0 = *(const bf16x8*)&Vs[cur][dr * 64 + ((lg ^ (dr & 7)) << 3)];
      const bf16x8 v1 = *(const bf16x8*)&Vs[cur][dr * 64 + (((lg + 4) ^ (dr & 7)) << 3)];
      oacc[n] = __builtin_amdgcn_mfma_f32_16x16x32_bf16(pf0, v0, oacc[n], 0, 0, 0);
      oacc[n] = __builtin_amdgcn_mfma_f32_16x16x32_bf16(pf1, v1, oacc[n], 0, 0, 0);
    }
    __builtin_amdgcn_s_setprio(0);
    __syncthreads();
  }

  // O: lane holds O[q = srow0 + lg*4 + r][d = n*16 + lr]
#pragma unroll
  for (int n = 0; n < 4; ++n) {
#pragma unroll
    for (int r = 0; r < 4; ++r) {
      const int s = srow0 + lg * 4 + r;
      Og[((size_t)(b * 2048 + s)) * 1024 + h * 64 + n * 16 + lr] = f2bf(oacc[n][r]);
    }
  }
}

// ---------------- launch ----------------
extern "C" void kernel_launch(void* const* d_in, const int* in_sizes, int n_in,
                              void* d_out, int out_size, void* d_ws, size_t ws_size,
                              hipStream_t stream) {
  const float* x     = (const float*)d_in[0];
  const int*   mask  = (const int*)d_in[1];
  const float* qkv_w = (const float*)d_in[2];
  const float* qkv_b = (const float*)d_in[3];
  const float* wo_w  = (const float*)d_in[4];
  const float* wo_b  = (const float*)d_in[5];
  float* out = (float*)d_out;

  char* ws = (char*)d_ws;
  u16* xb   = (u16*)(ws);                          // 4096x1024
  u16* qwb  = (u16*)(ws + (8u << 20));             // 3072x1024
  u16* wob  = (u16*)(ws + (14u << 20));            // 1024x1024
  u16* qkvb = (u16*)(ws + (16u << 20));            // Q,K: [bh][s][64] bf16 (V slot unused)
  u16* vt   = (u16*)(ws + (40u << 20));            // [bh][64][2048] bf16 (written by QKV epi)
  u16* ob   = (u16*)(ws + (48u << 20));            // attn out [4096][1024] bf16

  cvt3<<<8192, 256, 0, stream>>>(x, xb, qkv_w, qwb, wo_w, wob);
  gemm_bt<1, 128, 128><<<768, 256, 0, stream>>>(xb, qwb, qkv_b, qkvb, vt, 4096, 3072, 1024);
  attn<<<1024, 256, 0, stream>>>(qkvb, qkvb + 4194304, vt, mask, out + 4194304, ob);
  gemm_bt<0, 128, 64><<<512, 256, 0, stream>>>(ob, wob, wo_b, out, nullptr, 4096, 1024, 1024);
}

// Round 6
// 248.183 us; speedup vs baseline: 1.9500x; 1.0510x over previous
//
#include <hip/hip_runtime.h>
#include <cstdint>
#include <cstddef>

typedef unsigned short u16;
typedef __attribute__((ext_vector_type(8))) short bf16x8;
typedef __attribute__((ext_vector_type(4))) float f32x4;

#define DEV static __device__ __forceinline__

DEV void gload_lds16(const void* g, void* l) {
  __builtin_amdgcn_global_load_lds((const __attribute__((address_space(1))) void*)g,
                                   (__attribute__((address_space(3))) void*)l, 16, 0, 0);
}

DEV u16 f2bf(float f) {  // RNE fp32 -> bf16 (finite inputs)
  unsigned x = __float_as_uint(f);
  return (u16)((x + 0x7FFFu + ((x >> 16) & 1u)) >> 16);
}

DEV unsigned cvtpk(float lo, float hi) {  // bf16(lo) in [15:0], bf16(hi) in [31:16]
  unsigned r;
  asm("v_cvt_pk_bf16_f32 %0, %1, %2" : "=v"(r) : "v"(lo), "v"(hi));
  return r;
}

#if __has_builtin(__builtin_amdgcn_exp2f)
DEV float fexp2(float x) { return __builtin_amdgcn_exp2f(x); }
#else
DEV float fexp2(float x) { return exp2f(x); }
#endif

// counted vmcnt wait + scheduling fence (rule #18)
#define WAITV(n)                                                   \
  do {                                                             \
    asm volatile("s_waitcnt vmcnt(" #n ")" ::: "memory");          \
    __builtin_amdgcn_sched_barrier(0);                             \
  } while (0)

DEV void sbar() {
  __builtin_amdgcn_sched_barrier(0);
  __builtin_amdgcn_s_barrier();
  __builtin_amdgcn_sched_barrier(0);
}

// ---------------- fp32 -> bf16 convert, 3 buffers in one launch ----------------
__global__ __launch_bounds__(256) void cvt3(const float* __restrict__ a, u16* __restrict__ da,
                                            const float* __restrict__ b, u16* __restrict__ db,
                                            const float* __restrict__ c, u16* __restrict__ dc) {
  int bid = blockIdx.x;
  const float* s;
  u16* d;
  int base;
  if (bid < 4096) { s = a; d = da; base = bid; }
  else if (bid < 7168) { s = b; d = db; base = bid - 4096; }
  else { s = c; d = dc; base = bid - 7168; }
  const int i = (base * 256 + (int)threadIdx.x) * 4;
  float4 v = *(const float4*)(s + i);
  uint2 p;
  p.x = (unsigned)f2bf(v.x) | ((unsigned)f2bf(v.y) << 16);
  p.y = (unsigned)f2bf(v.z) | ((unsigned)f2bf(v.w) << 16);
  *(uint2*)(d + i) = p;
}

// ---------------- GEMM: C = A * B^T (+bias) ----------------
// A[M][K] bf16 row-major, Bm[N][K] bf16 row-major.
// EPI 0: Cout = float[M][N], v + bias[e]
// EPI 1: QKV scatter: Q,K -> [which][b*16+h][s][d] bf16; V -> Vt[b*16+h][d][s] (transposed)
template <int EPI, int BM, int BN>
__global__ __launch_bounds__(256) void gemm_bt(const u16* __restrict__ A,
                                               const u16* __restrict__ Bm,
                                               const float* __restrict__ bias,
                                               void* __restrict__ Cout,
                                               u16* __restrict__ Vt,
                                               int M, int N, int K) {
  __shared__ u16 As[2][BM * 32];
  __shared__ u16 Bs[2][BN * 32];
  constexpr int MT = BM / 32, NT = BN / 32;
  const int cpx = (int)gridDim.x >> 3;
  const int bid = ((int)blockIdx.x & 7) * cpx + ((int)blockIdx.x >> 3);  // XCD chunking
  const int nb = N / BN;
  const int m0 = (bid / nb) * BM;
  const int n0 = (bid % nb) * BN;
  const int tid = threadIdx.x;
  const int w = tid >> 6, lane = tid & 63;
  const int wm = (w >> 1) * (BM / 2), wn = (w & 1) * (BN / 2);
  const int lr = lane & 15, lg = lane >> 4;

  f32x4 acc[MT][NT];
  const f32x4 z4 = {0.f, 0.f, 0.f, 0.f};
#pragma unroll
  for (int m = 0; m < MT; ++m)
#pragma unroll
    for (int n = 0; n < NT; ++n) acc[m][n] = z4;

  auto stage = [&](int ks, int buf) {
    const int k0 = ks << 5;
#pragma unroll
    for (int i = 0; i < BM * 4 / 256; ++i) {
      const int o = i * 256 + tid;
      const int row = o >> 2, c = o & 3;
      gload_lds16(A + (size_t)(m0 + row) * K + k0 + c * 8, &As[buf][(i * 256 + w * 64) * 8]);
    }
#pragma unroll
    for (int i = 0; i < BN * 4 / 256; ++i) {
      const int o = i * 256 + tid;
      const int row = o >> 2, c = o & 3;
      gload_lds16(Bm + (size_t)(n0 + row) * K + k0 + c * 8, &Bs[buf][(i * 256 + w * 64) * 8]);
    }
  };

  const int nk = K >> 5;
  stage(0, 0);
  __syncthreads();
  for (int ks = 0; ks < nk; ++ks) {
    const int cur = ks & 1;
    if (ks + 1 < nk) stage(ks + 1, cur ^ 1);
    bf16x8 af[MT], bfr[NT];
#pragma unroll
    for (int m = 0; m < MT; ++m)
      af[m] = *(const bf16x8*)&As[cur][(wm + m * 16 + lr) * 32 + lg * 8];
#pragma unroll
    for (int n = 0; n < NT; ++n)
      bfr[n] = *(const bf16x8*)&Bs[cur][(wn + n * 16 + lr) * 32 + lg * 8];
    __builtin_amdgcn_s_setprio(1);
#pragma unroll
    for (int m = 0; m < MT; ++m)
#pragma unroll
      for (int n = 0; n < NT; ++n)
        acc[m][n] = __builtin_amdgcn_mfma_f32_16x16x32_bf16(af[m], bfr[n], acc[m][n], 0, 0, 0);
    __builtin_amdgcn_s_setprio(0);
    __syncthreads();
  }

#pragma unroll
  for (int n = 0; n < NT; ++n) {
    const int e = n0 + wn + n * 16 + lr;
    const float bv = bias[e];
    if (EPI == 1 && (e >> 10) == 2) {
      // V: write transposed [bh][d][s], 4 consecutive s packed per store
      const int h = (e >> 6) & 15, d = e & 63;
#pragma unroll
      for (int m = 0; m < MT; ++m) {
        const int row0 = m0 + wm + m * 16 + lg * 4;
        const int bb = row0 >> 11, s0 = row0 & 2047;
        uint2 pv;
        pv.x = cvtpk(acc[m][n][0] + bv, acc[m][n][1] + bv);
        pv.y = cvtpk(acc[m][n][2] + bv, acc[m][n][3] + bv);
        *(uint2*)(Vt + (size_t)(bb * 16 + h) * 131072 + (size_t)d * 2048 + s0) = pv;
      }
    } else {
#pragma unroll
      for (int m = 0; m < MT; ++m) {
#pragma unroll
        for (int r = 0; r < 4; ++r) {
          const int row = m0 + wm + m * 16 + lg * 4 + r;  // D: col=lane&15, row=(lane>>4)*4+r
          const float v = acc[m][n][r] + bv;
          if (EPI == 0) {
            ((float*)Cout)[(size_t)row * N + e] = v;
          } else {
            const int which = e >> 10, h = (e >> 6) & 15, d = e & 63;
            const int bb = row >> 11, s = row & 2047;
            ((u16*)Cout)[(size_t)which * 4194304 +
                         (((size_t)(bb * 16 + h) * 2048 + s) << 6) + d] = f2bf(v);
          }
        }
      }
    }
  }
}

// ---------------- fused attention: LDS-staged, counted-vmcnt raw barriers ----------------
// grid: 1024 blocks (XCD-chunked) = bh(32) x qtile(32). 4 waves x 16 q-rows.
// No __syncthreads: raw s_barrier + counted s_waitcnt vmcnt(N) (T3/T4) so the
// HBM-bound weight stores are NEVER drained inside the loop.
// Pass 1: K only, triple-buffered ring (Ks[0],Ks[1],Vs[0]), depth-2 prefetch, vmcnt(6).
// Pass 2: K+V double-buffered, depth-1 prefetch, vmcnt(8); nontemporal weight stores.
// Fixed-M0 softmax: p = exp2(s*log2e/8 - 8*log2e); masked -> 0.
__global__ __launch_bounds__(256, 4) void attn(const u16* __restrict__ Q,
                                               const u16* __restrict__ Kg,
                                               const u16* __restrict__ Vtg,
                                               const int* __restrict__ mask,
                                               float* __restrict__ Wout,
                                               u16* __restrict__ Og) {
  __shared__ u16 Ks[2][64 * 64];
  __shared__ u16 Vs[2][64 * 64];
  __shared__ u16 Pl[4][16 * 64];  // per-wave [16 q][64 t] bf16, XOR-swizzled (lr&7)<<4
  const int L = ((int)blockIdx.x & 7) * 128 + ((int)blockIdx.x >> 3);  // XCD chunking
  const int bh = L >> 5, qt = L & 31;
  const int b = bh >> 4, h = bh & 15;
  const int tid = threadIdx.x;
  const int w = tid >> 6, lane = tid & 63;
  const int lr = lane & 15, lg = lane >> 4;
  const int srow0 = qt * 64 + w * 16;
  const float C2 = 0.18033688011112042f;  // log2(e)/8
  const float M2 = 11.541560327111707f;   // 8*log2(e)

  const u16* qrow = Q + ((size_t)bh * 2048 + srow0 + lr) * 64;
  const bf16x8 qf0 = *(const bf16x8*)(qrow + lg * 8);
  const bf16x8 qf1 = *(const bf16x8*)(qrow + 32 + lg * 8);
  const int* mrow = mask + b * 2048;

  auto stageK = [&](int kt, u16* dst) {  // 2 gload_lds per thread
    const u16* g = Kg + (size_t)bh * 131072 + (size_t)kt * 4096;
#pragma unroll
    for (int iss = 0; iss < 2; ++iss) {
      const int o = iss * 256 + tid;
      const int row = o >> 3, c = o & 7;  // pre-swizzled global source, linear LDS dest
      gload_lds16(g + row * 64 + ((c ^ (row & 7)) << 3), dst + (iss * 256 + w * 64) * 8);
    }
  };
  auto stageV = [&](int kt, u16* dst) {  // 2 gload_lds per thread
    const u16* g = Vtg + (size_t)bh * 131072 + kt * 64;  // [d][t] rows, stride 2048
#pragma unroll
    for (int iss = 0; iss < 2; ++iss) {
      const int o = iss * 256 + tid;
      const int row = o >> 3, c = o & 7;
      gload_lds16(g + (size_t)row * 2048 + ((c ^ (row & 7)) << 3),
                  dst + (iss * 256 + w * 64) * 8);
    }
  };
  // pr[n][r] = unnormalized p for [q = srow0+lr][t = kt*64 + n*16 + lg*4 + r]
  // (issues 4 int4 mask loads -> counted in vmcnt budgets)
  auto probs = [&](const u16* kb, int kt, f32x4* pr) {
    int4 mv[4];
#pragma unroll
    for (int n = 0; n < 4; ++n) mv[n] = *(const int4*)&mrow[kt * 64 + n * 16 + lg * 4];
    f32x4 sc[4];
    __builtin_amdgcn_s_setprio(1);
#pragma unroll
    for (int n = 0; n < 4; ++n) {
      const int tr = n * 16 + lr;
      const bf16x8 k0 = *(const bf16x8*)&kb[tr * 64 + ((lg ^ (tr & 7)) << 3)];
      const bf16x8 k1 = *(const bf16x8*)&kb[tr * 64 + (((lg + 4) ^ (tr & 7)) << 3)];
      f32x4 s = {0.f, 0.f, 0.f, 0.f};
      s = __builtin_amdgcn_mfma_f32_16x16x32_bf16(k0, qf0, s, 0, 0, 0);
      s = __builtin_amdgcn_mfma_f32_16x16x32_bf16(k1, qf1, s, 0, 0, 0);
      sc[n] = s;
    }
    __builtin_amdgcn_s_setprio(0);
#pragma unroll
    for (int n = 0; n < 4; ++n) {
      f32x4 p;
      p[0] = (mv[n].x == 0) ? 0.f : fexp2(fmaf(sc[n][0], C2, -M2));
      p[1] = (mv[n].y == 0) ? 0.f : fexp2(fmaf(sc[n][1], C2, -M2));
      p[2] = (mv[n].z == 0) ? 0.f : fexp2(fmaf(sc[n][2], C2, -M2));
      p[3] = (mv[n].w == 0) ? 0.f : fexp2(fmaf(sc[n][3], C2, -M2));
      pr[n] = p;
    }
  };

  // ---- pass 1: per-lane denominator; K ring {Ks[0],Ks[1],Vs[0]}, depth-2 ----
  stageK(0, &Ks[0][0]);
  stageK(1, &Ks[1][0]);
  WAITV(2);  // L0 done; L1 in flight
  sbar();
  float lsum = 0.f;
  int cur3 = 0, stg3 = 2;
  for (int t = 0; t < 32; ++t) {
    u16* curb = (cur3 == 0) ? &Ks[0][0] : ((cur3 == 1) ? &Ks[1][0] : &Vs[0][0]);
    if (t + 2 < 32) {
      u16* stb = (stg3 == 0) ? &Ks[0][0] : ((stg3 == 1) ? &Ks[1][0] : &Vs[0][0]);
      stageK(t + 2, stb);
    }
    f32x4 pr[4];
    probs(curb, t, pr);
    float s0 = (pr[0][0] + pr[0][1]) + (pr[0][2] + pr[0][3]);
    float s1 = (pr[1][0] + pr[1][1]) + (pr[1][2] + pr[1][3]);
    float s2 = (pr[2][0] + pr[2][1]) + (pr[2][2] + pr[2][3]);
    float s3 = (pr[3][0] + pr[3][1]) + (pr[3][2] + pr[3][3]);
    lsum += (s0 + s1) + (s2 + s3);
    if (t + 1 < 32) {
      if (t + 2 < 32) {
        WAITV(6);  // L(t+1) done; L(t+2)[2] + mask(t)[4] may remain
      } else {
        WAITV(0);  // tail drain (cheap, once)
      }
      sbar();
    }
    cur3 = (cur3 == 2) ? 0 : cur3 + 1;
    stg3 = (stg3 == 2) ? 0 : stg3 + 1;
  }
  lsum += __shfl_xor(lsum, 16);
  lsum += __shfl_xor(lsum, 32);
  const float rl = 1.0f / lsum;

  // ---- pass 2: weights + PV; K+V double-buffer, depth-1, stores never drained ----
  sbar();  // all waves out of pass-1 reads before restaging
  f32x4 oacc[4];
  const f32x4 z4 = {0.f, 0.f, 0.f, 0.f};
#pragma unroll
  for (int n = 0; n < 4; ++n) oacc[n] = z4;

  float* wrow = Wout + ((size_t)bh * 2048 + srow0 + lr) * 2048;  // per-lane q-row
  char* plw = (char*)&Pl[w][0];
  const int pswz = (lr & 7) << 4;

  stageK(0, &Ks[0][0]);
  stageV(0, &Vs[0][0]);
  WAITV(0);
  sbar();
  for (int t = 0; t < 32; ++t) {
    const int cur = t & 1;
    if (t + 1 < 32) {
      stageK(t + 1, &Ks[cur ^ 1][0]);
      stageV(t + 1, &Vs[cur ^ 1][0]);
    }
    f32x4 pr[4];
    probs(&Ks[cur][0], t, pr);
#pragma unroll
    for (int n = 0; n < 4; ++n) {
      f32x4 wv;
      wv[0] = pr[n][0] * rl;
      wv[1] = pr[n][1] * rl;
      wv[2] = pr[n][2] * rl;
      wv[3] = pr[n][3] * rl;
      __builtin_nontemporal_store(wv, (f32x4*)&wrow[t * 64 + n * 16 + lg * 4]);
      uint2 pw;
      pw.x = cvtpk(wv[0], wv[1]);
      pw.y = cvtpk(wv[2], wv[3]);
      *(uint2*)(plw + (lr * 128 + ((n * 32 + lg * 8) ^ pswz))) = pw;
    }
    const bf16x8 pf0 = *(const bf16x8*)(plw + (lr * 128 + ((lg * 16) ^ pswz)));
    const bf16x8 pf1 = *(const bf16x8*)(plw + (lr * 128 + ((64 + lg * 16) ^ pswz)));
    __builtin_amdgcn_s_setprio(1);
#pragma unroll
    for (int n = 0; n < 4; ++n) {
      const int dr = n * 16 + lr;
      const bf16x8 v0 = *(const bf16x8*)&Vs[cur][dr * 64 + ((lg ^ (dr & 7)) << 3)];
      const bf16x8 v1 = *(const bf16x8*)&Vs[cur][dr * 64 + (((lg + 4) ^ (dr & 7)) << 3)];
      oacc[n] = __builtin_amdgcn_mfma_f32_16x16x32_bf16(pf0, v0, oacc[n], 0, 0, 0);
      oacc[n] = __builtin_amdgcn_mfma_f32_16x16x32_bf16(pf1, v1, oacc[n], 0, 0, 0);
    }
    __builtin_amdgcn_s_setprio(0);
    if (t + 1 < 32) {
      WAITV(8);  // stage(t+1) done; mask(t)[4] + stores(t)[4] may remain in flight
      sbar();
    }
  }

  // O: lane holds O[q = srow0 + lg*4 + r][d = n*16 + lr]
#pragma unroll
  for (int n = 0; n < 4; ++n) {
#pragma unroll
    for (int r = 0; r < 4; ++r) {
      const int s = srow0 + lg * 4 + r;
      Og[((size_t)(b * 2048 + s)) * 1024 + h * 64 + n * 16 + lr] = f2bf(oacc[n][r]);
    }
  }
}

// ---------------- launch ----------------
extern "C" void kernel_launch(void* const* d_in, const int* in_sizes, int n_in,
                              void* d_out, int out_size, void* d_ws, size_t ws_size,
                              hipStream_t stream) {
  const float* x     = (const float*)d_in[0];
  const int*   mask  = (const int*)d_in[1];
  const float* qkv_w = (const float*)d_in[2];
  const float* qkv_b = (const float*)d_in[3];
  const float* wo_w  = (const float*)d_in[4];
  const float* wo_b  = (const float*)d_in[5];
  float* out = (float*)d_out;

  char* ws = (char*)d_ws;
  u16* xb   = (u16*)(ws);                          // 4096x1024
  u16* qwb  = (u16*)(ws + (8u << 20));             // 3072x1024
  u16* wob  = (u16*)(ws + (14u << 20));            // 1024x1024
  u16* qkvb = (u16*)(ws + (16u << 20));            // Q,K: [bh][s][64] bf16 (V slot unused)
  u16* vt   = (u16*)(ws + (40u << 20));            // [bh][64][2048] bf16 (written by QKV epi)
  u16* ob   = (u16*)(ws + (48u << 20));            // attn out [4096][1024] bf16

  cvt3<<<8192, 256, 0, stream>>>(x, xb, qkv_w, qwb, wo_w, wob);
  gemm_bt<1, 128, 128><<<768, 256, 0, stream>>>(xb, qwb, qkv_b, qkvb, vt, 4096, 3072, 1024);
  attn<<<1024, 256, 0, stream>>>(qkvb, qkvb + 4194304, vt, mask, out + 4194304, ob);
  gemm_bt<0, 128, 64><<<512, 256, 0, stream>>>(ob, wob, wo_b, out, nullptr, 4096, 1024, 1024);
}